// Round 5
// baseline (13.465 us; speedup 1.0000x reference)
//
#include <hip/hip_runtime.h>
#include <hip/hip_bf16.h>

#define S_LEN 2048
#define H_NUM 8
#define D_DIM 64
#define W_WIN 32

typedef short bf16x8 __attribute__((ext_vector_type(8)));
typedef float f32x4  __attribute__((ext_vector_type(4)));

// 128-byte-row LDS tile swizzle: XOR bits 4-6 with row&7 (16-row access -> 2-way, free)
__device__ __forceinline__ int kswz(int row, int b) {
    return (row << 7) + (b ^ ((row & 7) << 4));
}
__device__ __forceinline__ short f2bf(float x) {
    __hip_bfloat16 h = __float2bfloat16(x);
    return *reinterpret_cast<short*>(&h);
}
__device__ __forceinline__ bf16x8 pack8(float4 a, float4 b) {
    bf16x8 r;
    r[0] = f2bf(a.x); r[1] = f2bf(a.y); r[2] = f2bf(a.z); r[3] = f2bf(a.w);
    r[4] = f2bf(b.x); r[5] = f2bf(b.y); r[6] = f2bf(b.z); r[7] = f2bf(b.w);
    return r;
}
__device__ __forceinline__ int sclamp(int s) {
    return s < 0 ? 0 : (s > S_LEN - 1 ? S_LEN - 1 : s);
}

// One wave (64 threads) per block; 16 queries per wave; everything direct
// from global into MFMA fragments. Only LDS use: 2 KB wave-local W transpose.
__global__ __launch_bounds__(64) void swa_gated_direct(
    const float* __restrict__ q, const float* __restrict__ k,
    const float* __restrict__ v, const float* __restrict__ a,
    const float* __restrict__ bgate, float* __restrict__ out)
{
    __shared__ __align__(16) unsigned short w_s[16 * 64];   // 2 KB
    char* wb = (char*)w_s;

    const int l  = threadIdx.x;
    const int lr = l & 15;
    const int lk = l >> 4;

    // bijective XCD swizzle (2048 blocks % 8 == 0): XCD x gets 2 full (b,h)
    // heads contiguously -> k+v+q working set ~3 MB < 4 MB L2
    const int bid  = blockIdx.x;
    const int orig = ((bid & 7) << 8) | (bid >> 3);
    const int tile = orig & 127;          // 128 tiles of 16 queries
    const int h    = (orig >> 7) & 7;
    const int bb   = orig >> 10;
    const int q0   = tile * 16;
    const size_t HD = (size_t)H_NUM * D_DIM;   // 512

    // ---- Q A-frags: lane (lr,lk) -> q[q0+lr][8lk..8lk+8) and +32 ----
    const float* qrow = q + ((size_t)(bb * S_LEN + q0 + lr)) * HD + (size_t)h * D_DIM + 8 * lk;
    bf16x8 aq0 = pack8(*(const float4*)(qrow),      *(const float4*)(qrow + 4));
    bf16x8 aq1 = pack8(*(const float4*)(qrow + 32), *(const float4*)(qrow + 36));

    // ---- scores: 3 n-tiles of 16 keys (cols 48..63 are never band-valid) ----
    f32x4 c[3];
    #pragma unroll
    for (int n = 0; n < 3; ++n) {
        int kseq = q0 - (W_WIN - 1) + 16 * n + lr;
        const float* krow = k + ((size_t)(bb * S_LEN + sclamp(kseq))) * HD + (size_t)h * D_DIM + 8 * lk;
        bf16x8 b0 = pack8(*(const float4*)(krow),      *(const float4*)(krow + 4));
        bf16x8 b1 = pack8(*(const float4*)(krow + 32), *(const float4*)(krow + 36));
        f32x4 z = {0.f, 0.f, 0.f, 0.f};
        z    = __builtin_amdgcn_mfma_f32_16x16x32_bf16(aq0, b0, z, 0, 0, 0);
        c[n] = __builtin_amdgcn_mfma_f32_16x16x32_bf16(aq1, b1, z, 0, 0, 0);
    }

    // ---- V B-frags direct from global: lane reads V[8 rows][d=16n+lr],
    //      4 rows x 16 consecutive floats per instr = fully coalesced ----
    const float* vcol = v + ((size_t)bb * S_LEN) * HD + (size_t)h * D_DIM + lr;
    bf16x8 vf0[4], vf1[4];
    #pragma unroll
    for (int n = 0; n < 4; ++n) {
        #pragma unroll
        for (int j = 0; j < 8; ++j) {
            int r0 = q0 - (W_WIN - 1) + 8 * lk + j;   // rows 0..31 of window
            vf0[n][j] = f2bf(vcol[(size_t)sclamp(r0)      * HD + 16 * n]);
            vf1[n][j] = f2bf(vcol[(size_t)sclamp(r0 + 32) * HD + 16 * n]);
        }
    }

    // ---- gate + band mask -> W (bf16) in wave-local LDS ----
    float bq[4];
    #pragma unroll
    for (int i = 0; i < 4; ++i)
        bq[i] = bgate[((size_t)(bb * S_LEN + q0 + 4 * lk + i)) * H_NUM + h];

    const float scale = 0.125f;   // 1/sqrt(64)
    #pragma unroll
    for (int n = 0; n < 3; ++n) {
        int j    = 16 * n + lr;                 // window col 0..47
        int kseq = q0 - (W_WIN - 1) + j;
        float av = a[((size_t)(bb * S_LEN + sclamp(kseq))) * H_NUM + h];
        #pragma unroll
        for (int i = 0; i < 4; ++i) {
            int qq = 4 * lk + i;                // query within tile
            bool valid = (j >= qq) && (j <= qq + 31) && (kseq >= 0);
            float g  = 1.0f / (1.0f + __expf(-(av * bq[i])));
            float wt = valid ? c[n][i] * scale * g : 0.0f;   // select: NaN-safe
            *(unsigned short*)(wb + kswz(qq, j * 2)) = (unsigned short)f2bf(wt);
        }
    }
    // zero W cols 48..63 (PV pads K to 64; V rows there are clamped-finite)
    *(uint2*)(wb + kswz(lr, 96 + 8 * lk)) = make_uint2(0u, 0u);

    // wave-local LDS round-trip: same-wave ds ordering + compiler lgkmcnt
    bf16x8 aw0 = *(const bf16x8*)(wb + kswz(lr, 16 * lk));
    bf16x8 aw1 = *(const bf16x8*)(wb + kswz(lr, 16 * lk + 64));

    // ---- PV + store ----
    float* obase = out + ((size_t)(bb * S_LEN + q0)) * HD + (size_t)h * D_DIM;
    #pragma unroll
    for (int n = 0; n < 4; ++n) {
        f32x4 z = {0.f, 0.f, 0.f, 0.f};
        z        = __builtin_amdgcn_mfma_f32_16x16x32_bf16(aw0, vf0[n], z, 0, 0, 0);
        f32x4 o  = __builtin_amdgcn_mfma_f32_16x16x32_bf16(aw1, vf1[n], z, 0, 0, 0);
        #pragma unroll
        for (int i = 0; i < 4; ++i) {
            obase[(size_t)(4 * lk + i) * HD + 16 * n + lr] = o[i];
        }
    }
}

extern "C" void kernel_launch(void* const* d_in, const int* in_sizes, int n_in,
                              void* d_out, int out_size, void* d_ws, size_t ws_size,
                              hipStream_t stream) {
    const float* q  = (const float*)d_in[0];
    const float* k  = (const float*)d_in[1];
    const float* v  = (const float*)d_in[2];
    const float* a  = (const float*)d_in[3];
    const float* bg = (const float*)d_in[4];
    float* out = (float*)d_out;

    dim3 grid(2 /*B*/ * H_NUM * (S_LEN / 16));   // 2048 one-wave blocks
    swa_gated_direct<<<grid, 64, 0, stream>>>(q, k, v, a, bg, out);
}